// Round 10
// baseline (343.889 us; speedup 1.0000x reference)
//
#include <hip/hip_runtime.h>
#include <hip/hip_bf16.h>
#include <stdint.h>

#define B_ 8
#define N_ 2048
#define F_ 64
#define FH_ 64
#define H_ 4
#define C_ (H_*FH_)
#define LOG2E 1.44269504088896340736f

typedef short short8 __attribute__((ext_vector_type(8)));   // 8 bf16 raw bits (4 VGPRs)
typedef float f32x4 __attribute__((ext_vector_type(4)));

// float -> bf16 raw bits (RNE)
__device__ __forceinline__ short f2bf(float f) {
    __hip_bfloat16 h = __float2bfloat16(f);
    return __builtin_bit_cast(short, h);
}

// ---------------- K0: WT[h][o][f] = bf16(W[h][f][o]) ----------------
__global__ __launch_bounds__(256) void k0_wt(const float* __restrict__ W,
                                             __hip_bfloat16* __restrict__ WT) {
    int idx = blockIdx.x * 256 + threadIdx.x;   // 16384 elems total
    int h = idx >> 12, rem = idx & 4095, o = rem >> 6, f = rem & 63;
    WT[idx] = __float2bfloat16(W[(h * F_ + f) * FH_ + o]);
}

// ---------------- KP: pack A (fp32 {0,1}) into a bitmask, 1 bit/edge ----------------
// Amask[row][j/64] bit l = (A[row][64k+l] != 0). 4 MB total -> L2-resident for k3.
// Pure streaming read: 64 consecutive 4B/lane per ballot.
__global__ __launch_bounds__(256) void kp_pack(const float* __restrict__ A,
                                               unsigned long long* __restrict__ Amask) {
    const int wave = threadIdx.x >> 6, lane = threadIdx.x & 63;
    const int R = blockIdx.x * 4 + wave;        // global row 0..16383 (= b*N + i)
    const float* arow = A + (size_t)R * N_;
    unsigned long long* mrow = Amask + (size_t)R * (N_ / 64);
#pragma unroll
    for (int i = 0; i < 8; ++i) {               // 8 x 256 cols
        float a0 = arow[i * 256 + lane];
        float a1 = arow[i * 256 + 64 + lane];
        float a2 = arow[i * 256 + 128 + lane];
        float a3 = arow[i * 256 + 192 + lane];
        unsigned long long m0 = __ballot(a0 != 0.0f);
        unsigned long long m1 = __ballot(a1 != 0.0f);
        unsigned long long m2 = __ballot(a2 != 0.0f);
        unsigned long long m3 = __ballot(a3 != 0.0f);
        if (lane == 0) {                        // ballot is wave-uniform
            mrow[i * 4 + 0] = m0; mrow[i * 4 + 1] = m1;
            mrow[i * 4 + 2] = m2; mrow[i * 4 + 3] = m3;
        }
    }
}

// ---------------- K1: featsT = (X@W)^T via MFMA, fused ss/sn epilogue ----------------
__global__ __launch_bounds__(256) void k1_feats(const float* __restrict__ X,
                                                const __hip_bfloat16* __restrict__ WT,
                                                const float* __restrict__ a_self,
                                                const float* __restrict__ a_neigh,
                                                __hip_bfloat16* __restrict__ featsT,
                                                float* __restrict__ ss,
                                                float* __restrict__ sn) {
    __shared__ float a_lds[2][FH_];
    __shared__ __hip_bfloat16 c_lds[FH_ * 72];  // padded leading dim 72 vs 64
    const int nb = blockIdx.x, h = blockIdx.y, b = blockIdx.z;
    const int tid = threadIdx.x;
    if (tid < 64)       a_lds[0][tid] = a_self[h * FH_ + tid];
    else if (tid < 128) a_lds[1][tid - 64] = a_neigh[h * FH_ + tid - 64];
    __syncthreads();

    const int wave = tid >> 6, lane = tid & 63;
    const int m = lane & 15, q = lane >> 4;
    const int nl = wave * 16 + m;               // local column 0..63
    const int n = nb * 64 + nl;                 // B-frag column (node index)
    f32x4 acc[4] = {};
#pragma unroll
    for (int ks = 0; ks < 2; ++ks) {            // K = F = 64, two steps of 32
        const float* xp = X + ((size_t)(b * N_ + n)) * F_ + ks * 32 + q * 8;
        float4 x0 = *(const float4*)xp;
        float4 x1 = *(const float4*)(xp + 4);
        short8 bfrag;
        bfrag[0] = f2bf(x0.x); bfrag[1] = f2bf(x0.y);
        bfrag[2] = f2bf(x0.z); bfrag[3] = f2bf(x0.w);
        bfrag[4] = f2bf(x1.x); bfrag[5] = f2bf(x1.y);
        bfrag[6] = f2bf(x1.z); bfrag[7] = f2bf(x1.w);
#pragma unroll
        for (int ot = 0; ot < 4; ++ot) {        // 64 output features = 4 row tiles
            short8 afrag = *(const short8*)(WT + ((size_t)(h * FH_ + ot * 16 + m)) * F_ + ks * 32 + q * 8);
            acc[ot] = __builtin_amdgcn_mfma_f32_16x16x32_bf16(afrag, bfrag, acc[ot], 0, 0, 0);
        }
    }
    float ssv = 0.f, snv = 0.f;
#pragma unroll
    for (int ot = 0; ot < 4; ++ot) {
#pragma unroll
        for (int r = 0; r < 4; ++r) {
            int orow = ot * 16 + q * 4 + r;     // C: row=(lane>>4)*4+r, col=lane&15
            float v = acc[ot][r];
            c_lds[orow * 72 + nl] = __float2bfloat16(v);
            ssv += v * a_lds[0][orow];
            snv += v * a_lds[1][orow];
        }
    }
    ssv += __shfl_xor(ssv, 16); ssv += __shfl_xor(ssv, 32);
    snv += __shfl_xor(snv, 16); snv += __shfl_xor(snv, 32);
    __syncthreads();
    {   // coalesced featsT store: thread t -> feature o = t>>2, 16-col chunk (t&3)
        int o = tid >> 2, c = (tid & 3) * 16;
        const __hip_bfloat16* src = c_lds + o * 72 + c;
        __hip_bfloat16* dst = featsT + ((size_t)(b * H_ + h) * FH_ + o) * N_ + nb * 64 + c;
        *(uint4*)dst       = *(const uint4*)src;        // 8 bf16
        *(uint4*)(dst + 8) = *(const uint4*)(src + 8);  // 8 bf16
    }
    if (lane < 16) {
        size_t idx = ((size_t)(b * H_ + h)) * N_ + n;
        ss[idx] = ssv * LOG2E;
        sn[idx] = snv * LOG2E;
    }
}

// ---------------- K3: fused mask+softmax(no-max)+PV MFMA + epilogue ----------------
// grid (N/64, H, B) = 1024 blocks; block = 1 head, 64 rows, 4 waves x 16 rows.
// A replaced by 4 MB bitmask (L2-resident): per iteration just 2 mask dwords +
// 8 featsT short8 (8 MB, L3-resident) -> all loads are cache-class latency.
// exp2(leaky(si+sj)) = max(e1i*e1j, e2i*e2j)  (leaky = max(s,0.2s), 2^x monotone).
__global__ __launch_bounds__(256, 4) void k3_attn(const unsigned int* __restrict__ Amask,
                                                  const __hip_bfloat16* __restrict__ featsT,
                                                  const float* __restrict__ ss,
                                                  const float* __restrict__ sn,
                                                  const float* __restrict__ bias,
                                                  float* __restrict__ out) {
    __shared__ float e1_lds[N_];                // 8 KB: 2^sn_j
    __shared__ float e2_lds[N_];                // 8 KB: 2^(0.2 sn_j)
    const int tile = blockIdx.x, h = blockIdx.y, b = blockIdx.z;
    const int tid = threadIdx.x, wave = tid >> 6, lane = tid & 63;
    const int m = lane & 15, q = lane >> 4;
    const int rowbase = tile * 64 + wave * 16;

    {   // stage this head's exp tables: 512 float4 slots, 2 per thread
        const float4* snrow = (const float4*)(sn + ((size_t)(b * H_ + h)) * N_);
        float4* e1v = (float4*)e1_lds;
        float4* e2v = (float4*)e2_lds;
#pragma unroll
        for (int i = 0; i < 2; ++i) {
            int idx = tid + i * 256;
            float4 v = snrow[idx];
            float4 u1, u2;
            u1.x = exp2f(v.x); u1.y = exp2f(v.y); u1.z = exp2f(v.z); u1.w = exp2f(v.w);
            u2.x = exp2f(0.2f * v.x); u2.y = exp2f(0.2f * v.y);
            u2.z = exp2f(0.2f * v.z); u2.w = exp2f(0.2f * v.w);
            e1v[idx] = u1; e2v[idx] = u2;
        }
    }
    const float ssi = ss[((size_t)(b * H_ + h)) * N_ + rowbase + m];
    const float e1i = exp2f(ssi), e2i = exp2f(0.2f * ssi);
    __syncthreads();

    const unsigned int* mrow = Amask + ((size_t)(b * N_) + rowbase + m) * (N_ / 32);
    const int shq = (q & 3) * 8;                // bit base within the mask word
    const int wq = q >> 2;                      // word offset for this q-group
    const __hip_bfloat16* fb = featsT + (((size_t)(b * H_ + h)) * FH_ + m) * N_ + q * 8;
    const float* t1 = e1_lds + q * 8;
    const float* t2 = e2_lds + q * 8;

    f32x4 accA[4] = {}, accB[4] = {};           // two independent chains (jb, jb+32)
    f32x4 acclA = {}, acclB = {};
    short8 ones;
#pragma unroll
    for (int s = 0; s < 8; ++s) ones[s] = (short)0x3F80;   // bf16 1.0

    for (int jb = 0; jb < N_; jb += 64) {
        unsigned int wAm = mrow[(jb >> 5) + wq];        // covers cols jb+q*8 .. +7
        unsigned int wBm = mrow[(jb >> 5) + 1 + wq];    // covers cols jb+32+q*8 .. +7
        short8 f0 = *(const short8*)(fb + jb);
        short8 f1 = *(const short8*)(fb + (size_t)16 * N_ + jb);
        short8 f2 = *(const short8*)(fb + (size_t)32 * N_ + jb);
        short8 f3 = *(const short8*)(fb + (size_t)48 * N_ + jb);
        short8 g0 = *(const short8*)(fb + jb + 32);
        short8 g1 = *(const short8*)(fb + (size_t)16 * N_ + jb + 32);
        short8 g2 = *(const short8*)(fb + (size_t)32 * N_ + jb + 32);
        short8 g3 = *(const short8*)(fb + (size_t)48 * N_ + jb + 32);
        float4 e1a0 = *(const float4*)(t1 + jb);
        float4 e1a1 = *(const float4*)(t1 + jb + 4);
        float4 e1b0 = *(const float4*)(t1 + jb + 32);
        float4 e1b1 = *(const float4*)(t1 + jb + 36);
        float4 e2a0 = *(const float4*)(t2 + jb);
        float4 e2a1 = *(const float4*)(t2 + jb + 4);
        float4 e2b0 = *(const float4*)(t2 + jb + 32);
        float4 e2b1 = *(const float4*)(t2 + jb + 36);

        float e1a[8] = {e1a0.x, e1a0.y, e1a0.z, e1a0.w, e1a1.x, e1a1.y, e1a1.z, e1a1.w};
        float e2a[8] = {e2a0.x, e2a0.y, e2a0.z, e2a0.w, e2a1.x, e2a1.y, e2a1.z, e2a1.w};
        float e1b[8] = {e1b0.x, e1b0.y, e1b0.z, e1b0.w, e1b1.x, e1b1.y, e1b1.z, e1b1.w};
        float e2b[8] = {e2b0.x, e2b0.y, e2b0.z, e2b0.w, e2b1.x, e2b1.y, e2b1.z, e2b1.w};

        short8 p0, p1;
#pragma unroll
        for (int s = 0; s < 8; ++s) {
            float vA = fmaxf(e1i * e1a[s], e2i * e2a[s]);   // exp2(leaky(si+sj))
            float vB = fmaxf(e1i * e1b[s], e2i * e2b[s]);
            p0[s] = (wAm & (1u << (shq + s))) ? f2bf(vA) : (short)0;
            p1[s] = (wBm & (1u << (shq + s))) ? f2bf(vB) : (short)0;
        }
        accA[0] = __builtin_amdgcn_mfma_f32_16x16x32_bf16(p0, f0, accA[0], 0, 0, 0);
        accB[0] = __builtin_amdgcn_mfma_f32_16x16x32_bf16(p1, g0, accB[0], 0, 0, 0);
        accA[1] = __builtin_amdgcn_mfma_f32_16x16x32_bf16(p0, f1, accA[1], 0, 0, 0);
        accB[1] = __builtin_amdgcn_mfma_f32_16x16x32_bf16(p1, g1, accB[1], 0, 0, 0);
        accA[2] = __builtin_amdgcn_mfma_f32_16x16x32_bf16(p0, f2, accA[2], 0, 0, 0);
        accB[2] = __builtin_amdgcn_mfma_f32_16x16x32_bf16(p1, g2, accB[2], 0, 0, 0);
        accA[3] = __builtin_amdgcn_mfma_f32_16x16x32_bf16(p0, f3, accA[3], 0, 0, 0);
        accB[3] = __builtin_amdgcn_mfma_f32_16x16x32_bf16(p1, g3, accB[3], 0, 0, 0);
        acclA   = __builtin_amdgcn_mfma_f32_16x16x32_bf16(p0, ones, acclA, 0, 0, 0);
        acclB   = __builtin_amdgcn_mfma_f32_16x16x32_bf16(p1, ones, acclB, 0, 0, 0);
    }

    float bc[4];
#pragma unroll
    for (int ct = 0; ct < 4; ++ct) bc[ct] = bias[h * FH_ + ct * 16 + m];

#pragma unroll
    for (int r = 0; r < 4; ++r) {
        float inv = 1.0f / (acclA[r] + acclB[r]);   // row sum (all cols identical)
        int gr = rowbase + q * 4 + r;
#pragma unroll
        for (int ct = 0; ct < 4; ++ct) {
            float v = (accA[ct][r] + accB[ct][r]) * inv + bc[ct];
            out[((size_t)(b * N_) + gr) * C_ + h * FH_ + ct * 16 + m] = fmaxf(v, 0.0f);
        }
    }
}

extern "C" void kernel_launch(void* const* d_in, const int* in_sizes, int n_in,
                              void* d_out, int out_size, void* d_ws, size_t ws_size,
                              hipStream_t stream) {
    const float* X       = (const float*)d_in[0];
    const float* A       = (const float*)d_in[1];
    const float* W       = (const float*)d_in[2];
    const float* bias    = (const float*)d_in[3];
    const float* a_self  = (const float*)d_in[4];
    const float* a_neigh = (const float*)d_in[5];
    float* out = (float*)d_out;   // reference output dtype is float32

    char* ws = (char*)d_ws;
    __hip_bfloat16* featsT = (__hip_bfloat16*)(ws);             // 8 MB   [B][H][FH][N]
    __hip_bfloat16* WT     = (__hip_bfloat16*)(ws + 8388608);   // 32 KB  [H][FH][F]
    float* ss              = (float*)(ws + 8421376);            // 256 KB [B][H][N]
    float* sn              = (float*)(ws + 8683520);            // 256 KB [B][H][N]
    unsigned long long* Am = (unsigned long long*)(ws + 8945664); // 4 MB bitmask

    k0_wt    <<<64, 256, 0, stream>>>(W, WT);
    kp_pack  <<<B_ * N_ / 4, 256, 0, stream>>>(A, Am);
    k1_feats <<<dim3(N_ / 64, H_, B_), 256, 0, stream>>>(X, WT, a_self, a_neigh, featsT, ss, sn);
    k3_attn  <<<dim3(N_ / 64, H_, B_), 256, 0, stream>>>((const unsigned int*)Am, featsT, ss, sn, bias, out);
}

// Round 11
// 258.484 us; speedup vs baseline: 1.3304x; 1.3304x over previous
//
#include <hip/hip_runtime.h>
#include <hip/hip_bf16.h>
#include <stdint.h>

#define B_ 8
#define N_ 2048
#define F_ 64
#define FH_ 64
#define H_ 4
#define C_ (H_*FH_)
#define CHUNK 128
#define NCHUNK (N_/CHUNK)
#define LOG2E 1.44269504088896340736f

typedef short short8 __attribute__((ext_vector_type(8)));   // 8 bf16 raw bits (4 VGPRs)
typedef float f32x4 __attribute__((ext_vector_type(4)));

// float -> bf16 raw bits (RNE)
__device__ __forceinline__ short f2bf(float f) {
    __hip_bfloat16 h = __float2bfloat16(f);
    return __builtin_bit_cast(short, h);
}

// async global->LDS DMA: lane l writes base + l*size; no VGPR destination, so the
// compiler cannot sink the load to its use site (R7-R10 lesson: it always sinks
// register prefetches). Verified mechanism per m03/m97.
__device__ __forceinline__ void async16(void* l, const void* g) {
    __builtin_amdgcn_global_load_lds((const __attribute__((address_space(1))) unsigned int*)g,
                                     (__attribute__((address_space(3))) unsigned int*)l, 16, 0, 0);
}
__device__ __forceinline__ void async4(void* l, const void* g) {
    __builtin_amdgcn_global_load_lds((const __attribute__((address_space(1))) unsigned int*)g,
                                     (__attribute__((address_space(3))) unsigned int*)l, 4, 0, 0);
}

// ---------------- K0: WT[h][o][f] = bf16(W[h][f][o]) ----------------
__global__ __launch_bounds__(256) void k0_wt(const float* __restrict__ W,
                                             __hip_bfloat16* __restrict__ WT) {
    int idx = blockIdx.x * 256 + threadIdx.x;   // 16384 elems total
    int h = idx >> 12, rem = idx & 4095, o = rem >> 6, f = rem & 63;
    WT[idx] = __float2bfloat16(W[(h * F_ + f) * FH_ + o]);
}

// ---------------- KP: pack A (fp32 {0,1}) into a bitmask, 1 bit/edge ----------------
__global__ __launch_bounds__(256) void kp_pack(const float* __restrict__ A,
                                               unsigned long long* __restrict__ Amask) {
    const int wave = threadIdx.x >> 6, lane = threadIdx.x & 63;
    const int R = blockIdx.x * 4 + wave;        // global row 0..16383 (= b*N + i)
    const float* arow = A + (size_t)R * N_;
    unsigned long long* mrow = Amask + (size_t)R * (N_ / 64);
#pragma unroll
    for (int i = 0; i < 8; ++i) {               // 8 x 256 cols
        float a0 = arow[i * 256 + lane];
        float a1 = arow[i * 256 + 64 + lane];
        float a2 = arow[i * 256 + 128 + lane];
        float a3 = arow[i * 256 + 192 + lane];
        unsigned long long m0 = __ballot(a0 != 0.0f);
        unsigned long long m1 = __ballot(a1 != 0.0f);
        unsigned long long m2 = __ballot(a2 != 0.0f);
        unsigned long long m3 = __ballot(a3 != 0.0f);
        if (lane == 0) {
            mrow[i * 4 + 0] = m0; mrow[i * 4 + 1] = m1;
            mrow[i * 4 + 2] = m2; mrow[i * 4 + 3] = m3;
        }
    }
}

// ---------------- K1: featsT = (X@W)^T via MFMA, fused ss/sn epilogue ----------------
__global__ __launch_bounds__(256) void k1_feats(const float* __restrict__ X,
                                                const __hip_bfloat16* __restrict__ WT,
                                                const float* __restrict__ a_self,
                                                const float* __restrict__ a_neigh,
                                                __hip_bfloat16* __restrict__ featsT,
                                                float* __restrict__ ss,
                                                float* __restrict__ sn) {
    __shared__ float a_lds[2][FH_];
    __shared__ __hip_bfloat16 c_lds[FH_ * 72];  // padded leading dim 72 vs 64
    const int nb = blockIdx.x, h = blockIdx.y, b = blockIdx.z;
    const int tid = threadIdx.x;
    if (tid < 64)       a_lds[0][tid] = a_self[h * FH_ + tid];
    else if (tid < 128) a_lds[1][tid - 64] = a_neigh[h * FH_ + tid - 64];
    __syncthreads();

    const int wave = tid >> 6, lane = tid & 63;
    const int m = lane & 15, q = lane >> 4;
    const int nl = wave * 16 + m;               // local column 0..63
    const int n = nb * 64 + nl;                 // B-frag column (node index)
    f32x4 acc[4] = {};
#pragma unroll
    for (int ks = 0; ks < 2; ++ks) {            // K = F = 64, two steps of 32
        const float* xp = X + ((size_t)(b * N_ + n)) * F_ + ks * 32 + q * 8;
        float4 x0 = *(const float4*)xp;
        float4 x1 = *(const float4*)(xp + 4);
        short8 bfrag;
        bfrag[0] = f2bf(x0.x); bfrag[1] = f2bf(x0.y);
        bfrag[2] = f2bf(x0.z); bfrag[3] = f2bf(x0.w);
        bfrag[4] = f2bf(x1.x); bfrag[5] = f2bf(x1.y);
        bfrag[6] = f2bf(x1.z); bfrag[7] = f2bf(x1.w);
#pragma unroll
        for (int ot = 0; ot < 4; ++ot) {
            short8 afrag = *(const short8*)(WT + ((size_t)(h * FH_ + ot * 16 + m)) * F_ + ks * 32 + q * 8);
            acc[ot] = __builtin_amdgcn_mfma_f32_16x16x32_bf16(afrag, bfrag, acc[ot], 0, 0, 0);
        }
    }
    float ssv = 0.f, snv = 0.f;
#pragma unroll
    for (int ot = 0; ot < 4; ++ot) {
#pragma unroll
        for (int r = 0; r < 4; ++r) {
            int orow = ot * 16 + q * 4 + r;     // C: row=(lane>>4)*4+r, col=lane&15
            float v = acc[ot][r];
            c_lds[orow * 72 + nl] = __float2bfloat16(v);
            ssv += v * a_lds[0][orow];
            snv += v * a_lds[1][orow];
        }
    }
    ssv += __shfl_xor(ssv, 16); ssv += __shfl_xor(ssv, 32);
    snv += __shfl_xor(snv, 16); snv += __shfl_xor(snv, 32);
    __syncthreads();
    {   // coalesced featsT store
        int o = tid >> 2, c = (tid & 3) * 16;
        const __hip_bfloat16* src = c_lds + o * 72 + c;
        __hip_bfloat16* dst = featsT + ((size_t)(b * H_ + h) * FH_ + o) * N_ + nb * 64 + c;
        *(uint4*)dst       = *(const uint4*)src;
        *(uint4*)(dst + 8) = *(const uint4*)(src + 8);
    }
    if (lane < 16) {
        size_t idx = ((size_t)(b * H_ + h)) * N_ + n;
        ss[idx] = ssv * LOG2E;
        sn[idx] = snv * LOG2E;
    }
}

// ---------------- K3: DMA-pipelined fused softmax+PV ----------------
// grid (N/128, H, B) = 512 blocks (2/CU, all resident); block = 1 head, 128 rows;
// wave w owns rows w*32..w*32+31 (2 sub-tiles of 16). K-loop over 16 chunks of 128
// cols: featsT chunk (16 KB, XOR-swizzled) + mask chunk (2 KB) DMA-staged (dbuf),
// one barrier per chunk. All in-loop reads are LDS; nothing for the compiler to sink.
__global__ __launch_bounds__(256, 2) void k3_attn(const unsigned int* __restrict__ Amask,
                                                  const __hip_bfloat16* __restrict__ featsT,
                                                  const float* __restrict__ ss,
                                                  const float* __restrict__ sn,
                                                  const float* __restrict__ bias,
                                                  float* __restrict__ out) {
    __shared__ __hip_bfloat16 fv_lds[2][64 * CHUNK];   // 2 x 16 KB, swizzled
    __shared__ unsigned int   mk_lds[2][128 * 4];      // 2 x 2 KB
    __shared__ float e1_lds[N_];                       // 8 KB: 2^sn_j
    __shared__ float e2_lds[N_];                       // 8 KB: 2^(0.2 sn_j)

    const int tile = blockIdx.x, h = blockIdx.y, b = blockIdx.z;
    const int tid = threadIdx.x, wave = tid >> 6, lane = tid & 63;
    const int m = lane & 15, q = lane >> 4;
    const int rowtile = tile * 128;

    {   // e-tables: 512 float4 slots, 2 per thread
        const float4* snrow = (const float4*)(sn + ((size_t)(b * H_ + h)) * N_);
        float4* e1v = (float4*)e1_lds;
        float4* e2v = (float4*)e2_lds;
#pragma unroll
        for (int i = 0; i < 2; ++i) {
            int idx = tid + i * 256;
            float4 v = snrow[idx];
            float4 u1, u2;
            u1.x = exp2f(v.x); u1.y = exp2f(v.y); u1.z = exp2f(v.z); u1.w = exp2f(v.w);
            u2.x = exp2f(0.2f * v.x); u2.y = exp2f(0.2f * v.y);
            u2.z = exp2f(0.2f * v.z); u2.w = exp2f(0.2f * v.w);
            e1v[idx] = u1; e2v[idx] = u2;
        }
    }
    const size_t srow = ((size_t)(b * H_ + h)) * N_ + rowtile + wave * 32 + m;
    const float ssi0 = ss[srow], ssi1 = ss[srow + 16];
    const float e1i0 = exp2f(ssi0), e2i0 = exp2f(0.2f * ssi0);
    const float e1i1 = exp2f(ssi1), e2i1 = exp2f(0.2f * ssi1);

    const __hip_bfloat16* fhead = featsT + ((size_t)(b * H_ + h)) * FH_ * N_;
    const unsigned int* mbase = Amask + ((size_t)(b * N_) + rowtile) * (N_ / 32);

    // ---- staging helpers (wave-uniform LDS base + lane*size, per HW contract) ----
    auto stage = [&](int c, int bufi) {
        const int cb = c * CHUNK;
#pragma unroll
        for (int i = 0; i < 4; ++i) {           // fv: 64 rows x 128 cols, swizzled
            int base_unit = i * 256 + wave * 64;
            int unit = base_unit + lane;
            int o = unit >> 4, v = unit & 15;
            int u = v ^ (o & 15);
            async16(&fv_lds[bufi][base_unit * 8], fhead + (size_t)o * N_ + cb + u * 8);
        }
#pragma unroll
        for (int i = 0; i < 2; ++i) {           // mask: 128 rows x 4 dwords
            int base_unit = i * 256 + wave * 64;
            int unit = base_unit + lane;
            int row = unit >> 2, dw = unit & 3;
            async4(&mk_lds[bufi][base_unit], mbase + (size_t)row * (N_ / 32) + (cb >> 5) + dw);
        }
    };

    stage(0, 0);
    __syncthreads();    // drains DMA (vmcnt) + e-table writes

    f32x4 acc[2][2][4] = {};    // [sub][chain][ct]
    f32x4 accl[2][2] = {};
    short8 ones;
#pragma unroll
    for (int s = 0; s < 8; ++s) ones[s] = (short)0x3F80;   // bf16 1.0

    for (int c = 0; c < NCHUNK; ++c) {
        const int cur = c & 1;
        if (c + 1 < NCHUNK) stage(c + 1, cur ^ 1);

#pragma unroll
        for (int jl = 0; jl < CHUNK; jl += 64) {
            const int cg = c * CHUNK + jl;
            // e-tables (broadcast within q-group)
            float4 eA10 = *(const float4*)(e1_lds + cg + q * 8);
            float4 eA11 = *(const float4*)(e1_lds + cg + q * 8 + 4);
            float4 eB10 = *(const float4*)(e1_lds + cg + 32 + q * 8);
            float4 eB11 = *(const float4*)(e1_lds + cg + 32 + q * 8 + 4);
            float4 eA20 = *(const float4*)(e2_lds + cg + q * 8);
            float4 eA21 = *(const float4*)(e2_lds + cg + q * 8 + 4);
            float4 eB20 = *(const float4*)(e2_lds + cg + 32 + q * 8);
            float4 eB21 = *(const float4*)(e2_lds + cg + 32 + q * 8 + 4);
            // fv fragments from swizzled LDS (<=2-way conflict -> free, m136)
            const int uA = (jl >> 3) + q, uB = ((jl + 32) >> 3) + q;
            short8 fA[4], fB[4];
#pragma unroll
            for (int ct = 0; ct < 4; ++ct) {
                int o = ct * 16 + m;
                fA[ct] = *(const short8*)(fv_lds[cur] + ((o << 4) + (uA ^ m)) * 8);
                fB[ct] = *(const short8*)(fv_lds[cur] + ((o << 4) + (uB ^ m)) * 8);
            }
            // mask dwords (broadcast within q-group)
            unsigned int mA0 = mk_lds[cur][(wave * 32 + m) * 4 + (jl >> 5)];
            unsigned int mB0 = mk_lds[cur][(wave * 32 + m) * 4 + (jl >> 5) + 1];
            unsigned int mA1 = mk_lds[cur][(wave * 32 + 16 + m) * 4 + (jl >> 5)];
            unsigned int mB1 = mk_lds[cur][(wave * 32 + 16 + m) * 4 + (jl >> 5) + 1];

            float e1A[8] = {eA10.x, eA10.y, eA10.z, eA10.w, eA11.x, eA11.y, eA11.z, eA11.w};
            float e1B[8] = {eB10.x, eB10.y, eB10.z, eB10.w, eB11.x, eB11.y, eB11.z, eB11.w};
            float e2A[8] = {eA20.x, eA20.y, eA20.z, eA20.w, eA21.x, eA21.y, eA21.z, eA21.w};
            float e2B[8] = {eB20.x, eB20.y, eB20.z, eB20.w, eB21.x, eB21.y, eB21.z, eB21.w};

            short8 pA0, pB0, pA1, pB1;
#pragma unroll
            for (int s = 0; s < 8; ++s) {
                // exp2(leaky(si+sj)) = max(e1i*e1j, e2i*e2j); mask via bit test
                float vA0 = fmaxf(e1i0 * e1A[s], e2i0 * e2A[s]);
                float vB0 = fmaxf(e1i0 * e1B[s], e2i0 * e2B[s]);
                float vA1 = fmaxf(e1i1 * e1A[s], e2i1 * e2A[s]);
                float vB1 = fmaxf(e1i1 * e1B[s], e2i1 * e2B[s]);
                const int bit = q * 8 + s;
                pA0[s] = (mA0 >> bit) & 1 ? f2bf(vA0) : (short)0;
                pB0[s] = (mB0 >> bit) & 1 ? f2bf(vB0) : (short)0;
                pA1[s] = (mA1 >> bit) & 1 ? f2bf(vA1) : (short)0;
                pB1[s] = (mB1 >> bit) & 1 ? f2bf(vB1) : (short)0;
            }
#pragma unroll
            for (int ct = 0; ct < 4; ++ct) {
                acc[0][0][ct] = __builtin_amdgcn_mfma_f32_16x16x32_bf16(pA0, fA[ct], acc[0][0][ct], 0, 0, 0);
                acc[0][1][ct] = __builtin_amdgcn_mfma_f32_16x16x32_bf16(pB0, fB[ct], acc[0][1][ct], 0, 0, 0);
                acc[1][0][ct] = __builtin_amdgcn_mfma_f32_16x16x32_bf16(pA1, fA[ct], acc[1][0][ct], 0, 0, 0);
                acc[1][1][ct] = __builtin_amdgcn_mfma_f32_16x16x32_bf16(pB1, fB[ct], acc[1][1][ct], 0, 0, 0);
            }
            accl[0][0] = __builtin_amdgcn_mfma_f32_16x16x32_bf16(pA0, ones, accl[0][0], 0, 0, 0);
            accl[0][1] = __builtin_amdgcn_mfma_f32_16x16x32_bf16(pB0, ones, accl[0][1], 0, 0, 0);
            accl[1][0] = __builtin_amdgcn_mfma_f32_16x16x32_bf16(pA1, ones, accl[1][0], 0, 0, 0);
            accl[1][1] = __builtin_amdgcn_mfma_f32_16x16x32_bf16(pB1, ones, accl[1][1], 0, 0, 0);
        }
        __syncthreads();    // drain next-chunk DMA; release cur buffer
    }

    float bc[4];
#pragma unroll
    for (int ct = 0; ct < 4; ++ct) bc[ct] = bias[h * FH_ + ct * 16 + m];

#pragma unroll
    for (int sub = 0; sub < 2; ++sub) {
#pragma unroll
        for (int r = 0; r < 4; ++r) {
            float inv = 1.0f / (accl[sub][0][r] + accl[sub][1][r]);
            int gr = rowtile + wave * 32 + sub * 16 + q * 4 + r;
#pragma unroll
            for (int ct = 0; ct < 4; ++ct) {
                float v = (acc[sub][0][ct][r] + acc[sub][1][ct][r]) * inv + bc[ct];
                out[((size_t)(b * N_) + gr) * C_ + h * FH_ + ct * 16 + m] = fmaxf(v, 0.0f);
            }
        }
    }
}

extern "C" void kernel_launch(void* const* d_in, const int* in_sizes, int n_in,
                              void* d_out, int out_size, void* d_ws, size_t ws_size,
                              hipStream_t stream) {
    const float* X       = (const float*)d_in[0];
    const float* A       = (const float*)d_in[1];
    const float* W       = (const float*)d_in[2];
    const float* bias    = (const float*)d_in[3];
    const float* a_self  = (const float*)d_in[4];
    const float* a_neigh = (const float*)d_in[5];
    float* out = (float*)d_out;   // reference output dtype is float32

    char* ws = (char*)d_ws;
    __hip_bfloat16* featsT = (__hip_bfloat16*)(ws);             // 8 MB   [B][H][FH][N]
    __hip_bfloat16* WT     = (__hip_bfloat16*)(ws + 8388608);   // 32 KB  [H][FH][F]
    float* ss              = (float*)(ws + 8421376);            // 256 KB [B][H][N]
    float* sn              = (float*)(ws + 8683520);            // 256 KB [B][H][N]
    unsigned long long* Am = (unsigned long long*)(ws + 8945664); // 4 MB bitmask

    k0_wt    <<<64, 256, 0, stream>>>(W, WT);
    kp_pack  <<<B_ * N_ / 4, 256, 0, stream>>>(A, Am);
    k1_feats <<<dim3(N_ / 64, H_, B_), 256, 0, stream>>>(X, WT, a_self, a_neigh, featsT, ss, sn);
    k3_attn  <<<dim3(N_ / CHUNK, H_, B_), 256, 0, stream>>>((const unsigned int*)Am, featsT, ss, sn, bias, out);
}

// Round 12
// 258.437 us; speedup vs baseline: 1.3306x; 1.0002x over previous
//
#include <hip/hip_runtime.h>
#include <hip/hip_bf16.h>
#include <stdint.h>

#define B_ 8
#define N_ 2048
#define F_ 64
#define FH_ 64
#define H_ 4
#define C_ (H_*FH_)
#define CHUNK 64
#define NCHUNK (N_/CHUNK)
#define LOG2E 1.44269504088896340736f

typedef short short8 __attribute__((ext_vector_type(8)));   // 8 bf16 raw bits (4 VGPRs)
typedef float f32x4 __attribute__((ext_vector_type(4)));

// float -> bf16 raw bits (RNE)
__device__ __forceinline__ short f2bf(float f) {
    __hip_bfloat16 h = __float2bfloat16(f);
    return __builtin_bit_cast(short, h);
}

// async global->LDS DMA: lane l writes base + l*size; no VGPR destination, so the
// compiler cannot sink it (R7-R10: register prefetches always get sunk; R11: DMA
// pipeline took k3 138 -> ~52 us).
__device__ __forceinline__ void async16(void* l, const void* g) {
    __builtin_amdgcn_global_load_lds((const __attribute__((address_space(1))) unsigned int*)g,
                                     (__attribute__((address_space(3))) unsigned int*)l, 16, 0, 0);
}
__device__ __forceinline__ void async4(void* l, const void* g) {
    __builtin_amdgcn_global_load_lds((const __attribute__((address_space(1))) unsigned int*)g,
                                     (__attribute__((address_space(3))) unsigned int*)l, 4, 0, 0);
}

// ---------------- K0: WT[h][o][f] = bf16(W[h][f][o]) ----------------
__global__ __launch_bounds__(256) void k0_wt(const float* __restrict__ W,
                                             __hip_bfloat16* __restrict__ WT) {
    int idx = blockIdx.x * 256 + threadIdx.x;   // 16384 elems total
    int h = idx >> 12, rem = idx & 4095, o = rem >> 6, f = rem & 63;
    WT[idx] = __float2bfloat16(W[(h * F_ + f) * FH_ + o]);
}

// ---------------- KP: pack A (fp32 {0,1}) into a bitmask, 1 bit/edge ----------------
__global__ __launch_bounds__(256) void kp_pack(const float* __restrict__ A,
                                               unsigned long long* __restrict__ Amask) {
    const int wave = threadIdx.x >> 6, lane = threadIdx.x & 63;
    const int R = blockIdx.x * 4 + wave;        // global row 0..16383 (= b*N + i)
    const float* arow = A + (size_t)R * N_;
    unsigned long long* mrow = Amask + (size_t)R * (N_ / 64);
#pragma unroll
    for (int i = 0; i < 8; ++i) {               // 8 x 256 cols
        float a0 = arow[i * 256 + lane];
        float a1 = arow[i * 256 + 64 + lane];
        float a2 = arow[i * 256 + 128 + lane];
        float a3 = arow[i * 256 + 192 + lane];
        unsigned long long m0 = __ballot(a0 != 0.0f);
        unsigned long long m1 = __ballot(a1 != 0.0f);
        unsigned long long m2 = __ballot(a2 != 0.0f);
        unsigned long long m3 = __ballot(a3 != 0.0f);
        if (lane == 0) {
            mrow[i * 4 + 0] = m0; mrow[i * 4 + 1] = m1;
            mrow[i * 4 + 2] = m2; mrow[i * 4 + 3] = m3;
        }
    }
}

// ---------------- K1: featsT = (X@W)^T via MFMA, fused ss/sn epilogue ----------------
__global__ __launch_bounds__(256) void k1_feats(const float* __restrict__ X,
                                                const __hip_bfloat16* __restrict__ WT,
                                                const float* __restrict__ a_self,
                                                const float* __restrict__ a_neigh,
                                                __hip_bfloat16* __restrict__ featsT,
                                                float* __restrict__ ss,
                                                float* __restrict__ sn) {
    __shared__ float a_lds[2][FH_];
    __shared__ __hip_bfloat16 c_lds[FH_ * 72];  // padded leading dim 72 vs 64
    const int nb = blockIdx.x, h = blockIdx.y, b = blockIdx.z;
    const int tid = threadIdx.x;
    if (tid < 64)       a_lds[0][tid] = a_self[h * FH_ + tid];
    else if (tid < 128) a_lds[1][tid - 64] = a_neigh[h * FH_ + tid - 64];
    __syncthreads();

    const int wave = tid >> 6, lane = tid & 63;
    const int m = lane & 15, q = lane >> 4;
    const int nl = wave * 16 + m;               // local column 0..63
    const int n = nb * 64 + nl;                 // B-frag column (node index)
    f32x4 acc[4] = {};
#pragma unroll
    for (int ks = 0; ks < 2; ++ks) {            // K = F = 64, two steps of 32
        const float* xp = X + ((size_t)(b * N_ + n)) * F_ + ks * 32 + q * 8;
        float4 x0 = *(const float4*)xp;
        float4 x1 = *(const float4*)(xp + 4);
        short8 bfrag;
        bfrag[0] = f2bf(x0.x); bfrag[1] = f2bf(x0.y);
        bfrag[2] = f2bf(x0.z); bfrag[3] = f2bf(x0.w);
        bfrag[4] = f2bf(x1.x); bfrag[5] = f2bf(x1.y);
        bfrag[6] = f2bf(x1.z); bfrag[7] = f2bf(x1.w);
#pragma unroll
        for (int ot = 0; ot < 4; ++ot) {
            short8 afrag = *(const short8*)(WT + ((size_t)(h * FH_ + ot * 16 + m)) * F_ + ks * 32 + q * 8);
            acc[ot] = __builtin_amdgcn_mfma_f32_16x16x32_bf16(afrag, bfrag, acc[ot], 0, 0, 0);
        }
    }
    float ssv = 0.f, snv = 0.f;
#pragma unroll
    for (int ot = 0; ot < 4; ++ot) {
#pragma unroll
        for (int r = 0; r < 4; ++r) {
            int orow = ot * 16 + q * 4 + r;     // C: row=(lane>>4)*4+r, col=lane&15
            float v = acc[ot][r];
            c_lds[orow * 72 + nl] = __float2bfloat16(v);
            ssv += v * a_lds[0][orow];
            snv += v * a_lds[1][orow];
        }
    }
    ssv += __shfl_xor(ssv, 16); ssv += __shfl_xor(ssv, 32);
    snv += __shfl_xor(snv, 16); snv += __shfl_xor(snv, 32);
    __syncthreads();
    {   // coalesced featsT store
        int o = tid >> 2, c = (tid & 3) * 16;
        const __hip_bfloat16* src = c_lds + o * 72 + c;
        __hip_bfloat16* dst = featsT + ((size_t)(b * H_ + h) * FH_ + o) * N_ + nb * 64 + c;
        *(uint4*)dst       = *(const uint4*)src;
        *(uint4*)(dst + 8) = *(const uint4*)(src + 8);
    }
    if (lane < 16) {
        size_t idx = ((size_t)(b * H_ + h)) * N_ + n;
        ss[idx] = ssv * LOG2E;
        sn[idx] = snv * LOG2E;
    }
}

// ---------------- K3: DMA-pipelined fused softmax+PV ----------------
// grid (N/64, H, B) = 1024 blocks = 4/CU (grid-capped; LDS 33 KB also allows 4)
// -> 16 waves/CU (R11 had 8). Block = 1 head, 64 rows; wave owns 16 rows.
// K-loop: 32 chunks of 64 cols; fv chunk (8 KB, XOR-swizzled) + mask chunk (512 B)
// DMA-staged double-buffered; one barrier per chunk; inner loop reads LDS only.
__global__ __launch_bounds__(256, 4) void k3_attn(const unsigned int* __restrict__ Amask,
                                                  const __hip_bfloat16* __restrict__ featsT,
                                                  const float* __restrict__ ss,
                                                  const float* __restrict__ sn,
                                                  const float* __restrict__ bias,
                                                  float* __restrict__ out) {
    __shared__ __hip_bfloat16 fv_lds[2][64 * CHUNK];   // 2 x 8 KB, swizzled
    __shared__ unsigned int   mk_lds[2][64 * 2];       // 2 x 512 B
    __shared__ float e1_lds[N_];                       // 8 KB: 2^sn_j
    __shared__ float e2_lds[N_];                       // 8 KB: 2^(0.2 sn_j)

    const int tile = blockIdx.x, h = blockIdx.y, b = blockIdx.z;
    const int tid = threadIdx.x, wave = tid >> 6, lane = tid & 63;
    const int m = lane & 15, q = lane >> 4;
    const int rowtile = tile * 64;

    {   // e-tables: 512 float4 slots, 2 per thread
        const float4* snrow = (const float4*)(sn + ((size_t)(b * H_ + h)) * N_);
        float4* e1v = (float4*)e1_lds;
        float4* e2v = (float4*)e2_lds;
#pragma unroll
        for (int i = 0; i < 2; ++i) {
            int idx = tid + i * 256;
            float4 v = snrow[idx];
            float4 u1, u2;
            u1.x = exp2f(v.x); u1.y = exp2f(v.y); u1.z = exp2f(v.z); u1.w = exp2f(v.w);
            u2.x = exp2f(0.2f * v.x); u2.y = exp2f(0.2f * v.y);
            u2.z = exp2f(0.2f * v.z); u2.w = exp2f(0.2f * v.w);
            e1v[idx] = u1; e2v[idx] = u2;
        }
    }
    const float ssi = ss[((size_t)(b * H_ + h)) * N_ + rowtile + wave * 16 + m];
    const float e1i = exp2f(ssi), e2i = exp2f(0.2f * ssi);

    const __hip_bfloat16* fhead = featsT + ((size_t)(b * H_ + h)) * FH_ * N_;
    const unsigned int* mbase = Amask + ((size_t)(b * N_) + rowtile) * (N_ / 32);

    // stage chunk c into buffer bufi (wave-uniform LDS base + lane*size per HW contract)
    auto stage = [&](int c, int bufi) {
        const int cb = c * CHUNK;
#pragma unroll
        for (int i = 0; i < 2; ++i) {           // fv: 64 feats x 64 cols, 512 16B-units
            int base_unit = i * 256 + wave * 64;
            int unit = base_unit + lane;
            int o = unit >> 3, v = unit & 7;
            int u = v ^ (o & 7);                // XOR swizzle (compute-side <=optimal)
            async16(&fv_lds[bufi][base_unit * 8], fhead + (size_t)o * N_ + cb + u * 8);
        }
        if (wave < 2) {                         // mask: 64 rows x 2 dwords = 128 units
            int base_unit = wave * 64;
            int unit = base_unit + lane;
            int row = unit >> 1, dw = unit & 1;
            async4(&mk_lds[bufi][base_unit], mbase + (size_t)row * (N_ / 32) + (cb >> 5) + dw);
        }
    };

    stage(0, 0);
    __syncthreads();    // drains DMA (vmcnt) + e-table LDS writes

    f32x4 acc[2][4] = {};       // [chain][ct]
    f32x4 accl[2] = {};
    short8 ones;
#pragma unroll
    for (int s = 0; s < 8; ++s) ones[s] = (short)0x3F80;   // bf16 1.0

    for (int c = 0; c < NCHUNK; ++c) {
        const int cur = c & 1;
        if (c + 1 < NCHUNK) stage(c + 1, cur ^ 1);

        const int cg = c * CHUNK;
        // e-tables (broadcast within q-group -> near-free LDS reads)
        float4 eA10 = *(const float4*)(e1_lds + cg + q * 8);
        float4 eA11 = *(const float4*)(e1_lds + cg + q * 8 + 4);
        float4 eB10 = *(const float4*)(e1_lds + cg + 32 + q * 8);
        float4 eB11 = *(const float4*)(e1_lds + cg + 32 + q * 8 + 4);
        float4 eA20 = *(const float4*)(e2_lds + cg + q * 8);
        float4 eA21 = *(const float4*)(e2_lds + cg + q * 8 + 4);
        float4 eB20 = *(const float4*)(e2_lds + cg + 32 + q * 8);
        float4 eB21 = *(const float4*)(e2_lds + cg + 32 + q * 8 + 4);
        // fv fragments: chain A = col-units 0..3 (uA=q), chain B = units 4..7
        short8 fA[4], fB[4];
#pragma unroll
        for (int ct = 0; ct < 4; ++ct) {
            int o = ct * 16 + m;
            fA[ct] = *(const short8*)(fv_lds[cur] + ((o << 3) + (q ^ (o & 7))) * 8);
            fB[ct] = *(const short8*)(fv_lds[cur] + ((o << 3) + ((4 + q) ^ (o & 7))) * 8);
        }
        // mask dwords for this row (broadcast within q-group)
        unsigned int mA = mk_lds[cur][(wave * 16 + m) * 2];
        unsigned int mB = mk_lds[cur][(wave * 16 + m) * 2 + 1];

        float e1A[8] = {eA10.x, eA10.y, eA10.z, eA10.w, eA11.x, eA11.y, eA11.z, eA11.w};
        float e1B[8] = {eB10.x, eB10.y, eB10.z, eB10.w, eB11.x, eB11.y, eB11.z, eB11.w};
        float e2A[8] = {eA20.x, eA20.y, eA20.z, eA20.w, eA21.x, eA21.y, eA21.z, eA21.w};
        float e2B[8] = {eB20.x, eB20.y, eB20.z, eB20.w, eB21.x, eB21.y, eB21.z, eB21.w};

        short8 pA, pB;
#pragma unroll
        for (int s = 0; s < 8; ++s) {
            // exp2(leaky(si+sj)) = max(e1i*e1j, e2i*e2j); adjacency via bit test
            float vA = fmaxf(e1i * e1A[s], e2i * e2A[s]);
            float vB = fmaxf(e1i * e1B[s], e2i * e2B[s]);
            const int bit = q * 8 + s;
            pA[s] = (mA >> bit) & 1 ? f2bf(vA) : (short)0;
            pB[s] = (mB >> bit) & 1 ? f2bf(vB) : (short)0;
        }
#pragma unroll
        for (int ct = 0; ct < 4; ++ct) {
            acc[0][ct] = __builtin_amdgcn_mfma_f32_16x16x32_bf16(pA, fA[ct], acc[0][ct], 0, 0, 0);
            acc[1][ct] = __builtin_amdgcn_mfma_f32_16x16x32_bf16(pB, fB[ct], acc[1][ct], 0, 0, 0);
        }
        accl[0] = __builtin_amdgcn_mfma_f32_16x16x32_bf16(pA, ones, accl[0], 0, 0, 0);
        accl[1] = __builtin_amdgcn_mfma_f32_16x16x32_bf16(pB, ones, accl[1], 0, 0, 0);

        __syncthreads();    // drain next-chunk DMA; release cur buffer
    }

    float bc[4];
#pragma unroll
    for (int ct = 0; ct < 4; ++ct) bc[ct] = bias[h * FH_ + ct * 16 + m];

#pragma unroll
    for (int r = 0; r < 4; ++r) {
        float inv = 1.0f / (accl[0][r] + accl[1][r]);   // row sum (all cols identical)
        int gr = rowtile + wave * 16 + q * 4 + r;
#pragma unroll
        for (int ct = 0; ct < 4; ++ct) {
            float v = (acc[0][ct][r] + acc[1][ct][r]) * inv + bc[ct];
            out[((size_t)(b * N_) + gr) * C_ + h * FH_ + ct * 16 + m] = fmaxf(v, 0.0f);
        }
    }
}

extern "C" void kernel_launch(void* const* d_in, const int* in_sizes, int n_in,
                              void* d_out, int out_size, void* d_ws, size_t ws_size,
                              hipStream_t stream) {
    const float* X       = (const float*)d_in[0];
    const float* A       = (const float*)d_in[1];
    const float* W       = (const float*)d_in[2];
    const float* bias    = (const float*)d_in[3];
    const float* a_self  = (const float*)d_in[4];
    const float* a_neigh = (const float*)d_in[5];
    float* out = (float*)d_out;   // reference output dtype is float32

    char* ws = (char*)d_ws;
    __hip_bfloat16* featsT = (__hip_bfloat16*)(ws);             // 8 MB   [B][H][FH][N]
    __hip_bfloat16* WT     = (__hip_bfloat16*)(ws + 8388608);   // 32 KB  [H][FH][F]
    float* ss              = (float*)(ws + 8421376);            // 256 KB [B][H][N]
    float* sn              = (float*)(ws + 8683520);            // 256 KB [B][H][N]
    unsigned long long* Am = (unsigned long long*)(ws + 8945664); // 4 MB bitmask

    k0_wt    <<<64, 256, 0, stream>>>(W, WT);
    kp_pack  <<<B_ * N_ / 4, 256, 0, stream>>>(A, Am);
    k1_feats <<<dim3(N_ / 64, H_, B_), 256, 0, stream>>>(X, WT, a_self, a_neigh, featsT, ss, sn);
    k3_attn  <<<dim3(N_ / 64, H_, B_), 256, 0, stream>>>((const unsigned int*)Am, featsT, ss, sn, bias, out);
}